// Round 7
// baseline (1748.084 us; speedup 1.0000x reference)
//
#include <hip/hip_runtime.h>
#include <stdint.h>

// Problem constants
#define TS 64
#define BATCH 1024
#define HID 256
#define IMGD 2048

typedef __bf16 bf16_t;
typedef bf16_t bf16x8 __attribute__((ext_vector_type(8)));
typedef float f32x4 __attribute__((ext_vector_type(4)));

// load 8 consecutive fp32 (16B-aligned) and convert to a bf16x8 MFMA fragment
static __device__ __forceinline__ bf16x8 cvt8(const float* __restrict__ p) {
    const f32x4 a = *reinterpret_cast<const f32x4*>(p);
    const f32x4 b = *reinterpret_cast<const f32x4*>(p + 4);
    bf16x8 r;
    r[0] = (bf16_t)a[0]; r[1] = (bf16_t)a[1]; r[2] = (bf16_t)a[2]; r[3] = (bf16_t)a[3];
    r[4] = (bf16_t)b[0]; r[5] = (bf16_t)b[1]; r[6] = (bf16_t)b[2]; r[7] = (bf16_t)b[3];
    return r;
}
// pack 4 f32 -> u64 of 4 bf16 (same RNE cast as cvt8 -> numerics match old kernel)
static __device__ __forceinline__ unsigned long long pack4(f32x4 v) {
    union { unsigned long long u; bf16_t b[4]; } c;
    c.b[0] = (bf16_t)v[0]; c.b[1] = (bf16_t)v[1];
    c.b[2] = (bf16_t)v[2]; c.b[3] = (bf16_t)v[3];
    return c.u;
}
static __device__ __forceinline__ float sigm(float x) { return 1.f / (1.f + __expf(-x)); }
static __device__ __forceinline__ float tanh_f(float x) { return 1.f - 2.f / (1.f + __expf(2.f * x)); }

// ---------------------------------------------------------------------------
// ROUND-11 REDESIGN — no inter-block communication at all.
//
// Evidence: the 4-block h-exchange costs ~13k cy/step in serial MALL hops
// (r6 -23% from transaction count; r5/r7 neutral on everything else); three
// container-failed rounds trying to cheapen those hops via sc0/XCD tricks.
// The exchange exists only because 4 blocks share the weights in registers.
// This round: ONE 1024-thread block owns a full batch group (16 rows x all
// 256 units). h(t) lives in LDS; per-step sync = one __syncthreads (~100cy).
// Weights (1MB bf16, too big for any register file) stream from a shared
// L2-resident copy every step: ~1MB/block/step -> ~8MB/XCD/step ~ 1-2us,
// overlapped with MFMA. Deadlock-free by construction: no flags, no spins,
// all barriers block-uniform.
//
// prep_kernel (256x256, runs first on the stream):
//   - converts W_ih/W_hh f32 -> bf16 in FRAGMENT-MAJOR layout, so each
//     weight fragment load in the LSTM loop is one fully-coalesced 1KB
//     wave transaction: Wsw[fid][lane] 16B, fid = A*512 + (q*16+v)*8 + kk.
//   - computes the img branch (relu(img @ W_img^T + b)) into IMG[1024][256].
// lstm_kernel (64x1024): 16 waves; wave v owns unit-tile [16v,16v+16);
//   lane (quad,j) owns units 16v+quad*4..+3 x batch row b0+j -> the LSTM
//   cell is lane-local (identical fragment mapping to the r4-verified
//   kernel). x tile and h tile in XOR-swizzled LDS (r4-verified swizzle).
//
// CRITICAL (round-4 lesson): all register-array indices compile-time
// constant; loops fully unrolled.
// Workspace: Wsw 1MB @ ws+0, IMG 1MB @ ws+1MB (no memset needed: prep
// writes every byte kernel 2 reads).
// ---------------------------------------------------------------------------

__global__ __launch_bounds__(256, 1) void prep_kernel(
    const float* __restrict__ img_feature, const float* __restrict__ W_img,
    const float* __restrict__ b_img,
    const float* __restrict__ W_ih, const float* __restrict__ W_hh,
    unsigned long long* __restrict__ Wsw, float* __restrict__ IMG)
{
    const int g = blockIdx.x & 63, ch = blockIdx.x >> 6;
    const int b0 = g * 16, u0 = ch * 64;
    const int w = threadIdx.x >> 6, lane = threadIdx.x & 63;
    const int quad = lane >> 4, j = lane & 15;
    const int uw = u0 + w * 16;
    const int ulane = uw + quad * 4;
    const int brow = b0 + j;

    // ---- weight swizzle: this wave emits one 1KB fragment-block
    {
        const int fid = blockIdx.x * 4 + w;      // 0..1023
        const int A = fid >> 9;                  // 0 = ih, 1 = hh
        const int f = fid & 511;
        const int kk = f & 7, mt = f >> 3;       // mt = q*16 + v
        const int row = (mt >> 4) * HID + (mt & 15) * 16 + j;
        const int col = kk * 32 + quad * 8;
        const float* src = (A ? W_hh : W_ih) + (size_t)row * HID + col;
        *reinterpret_cast<bf16x8*>((char*)Wsw + (size_t)fid * 1024 + lane * 16) = cvt8(src);
    }

    // ---- img tile (verbatim from the r4-passing prologue), stored to IMG
    f32x4 D = {};
    const float* aw = W_img + (size_t)(uw + j) * IMGD + quad * 8;
    const float* bx = img_feature + (size_t)brow * IMGD + quad * 8;
    for (int kk = 0; kk < 64; ++kk) {
        bf16x8 a = cvt8(aw + kk * 32);
        bf16x8 b = cvt8(bx + kk * 32);
        D = __builtin_amdgcn_mfma_f32_16x16x32_bf16(a, b, D, 0, 0, 0);
    }
    f32x4 o;
#pragma unroll
    for (int r = 0; r < 4; ++r) {
        float vv = D[r] + b_img[ulane + r];
        o[r] = vv > 0.f ? vv : 0.f;
    }
    *reinterpret_cast<f32x4*>(IMG + (size_t)brow * HID + ulane) = o;
}

__global__ __launch_bounds__(1024, 4) void lstm_kernel(
    const int* __restrict__ caption, const float* __restrict__ emb,
    const float* __restrict__ b_ih, const float* __restrict__ b_hh,
    const unsigned long long* __restrict__ Wsw, const float* __restrict__ IMG,
    float* __restrict__ out)
{
    const int g = blockIdx.x;            // 0..63: batch group
    const int b0 = g * 16;
    const int tid = (int)threadIdx.x;
    const int v = tid >> 6, lane = tid & 63;
    const int quad = lane >> 4, j = lane & 15;
    const int ulane = v * 16 + quad * 4; // lane's first unit (owns 4)
    const int brow = b0 + j;             // lane's batch row

    // swizzled tiles: phys(row r, byte b) = r*512 + (b ^ (r<<4))  [r4-verified]
    __shared__ unsigned long long hbuf[2][1024];   // h(t) bf16, 8KB each
    __shared__ unsigned long long xbuf[2][1024];   // x(t) bf16, 8KB each

    // cooperative x-gather coords: 16 rows x 64 four-float segments
    const int grow = tid >> 6;           // 0..15 (== v)
    const int gseg = tid & 63;           // 0..63

    // ---- per-lane constants
    const f32x4 imgv = *reinterpret_cast<const f32x4*>(IMG + (size_t)brow * HID + ulane);
    f32x4 biasv[4];
#pragma unroll
    for (int q = 0; q < 4; ++q)
#pragma unroll
        for (int r = 0; r < 4; ++r)
            biasv[q][r] = b_ih[q * HID + ulane + r] + b_hh[q * HID + ulane + r];

    float cst[4] = {0.f, 0.f, 0.f, 0.f};

    // ---- stage x(0)
    {
        int cap = caption[b0 + grow];
        f32x4 xv = *reinterpret_cast<const f32x4*>(emb + (size_t)cap * HID + gseg * 4);
        *(unsigned long long*)((char*)xbuf[0] + grow * 512 + ((gseg * 8) ^ (grow << 4))) = pack4(xv);
    }
    __syncthreads();

    // wave weight base: fid = A*512 + (q*16+v)*8 + kk = A*512 + q*128 + v*8 + kk
    const char* wv = (const char*)Wsw + (size_t)(v * 8) * 1024 + (size_t)lane * 16;

    for (int t = 0; t < TS; ++t) {
        // ---- 1. issue next-step x gather (consumed at phase 3)
        f32x4 xv;
        const bool have_x = (t + 1 < TS);
        if (have_x) {
            int cap = caption[(t + 1) * BATCH + b0 + grow];
            xv = *reinterpret_cast<const f32x4*>(emb + (size_t)cap * HID + gseg * 4);
        }

        // ---- 2. gates GEMM: C = bias + W_ih@x(t) + W_hh@h(t-1)
        f32x4 C[4];
#pragma unroll
        for (int q = 0; q < 4; ++q) C[q] = biasv[q];

        {
            const char* xb = (const char*)xbuf[t & 1];
#pragma unroll
            for (int kk = 0; kk < 8; ++kk) {
                bf16x8 bx = *reinterpret_cast<const bf16x8*>(
                    xb + j * 512 + ((kk * 64 + quad * 16) ^ (j << 4)));
#pragma unroll
                for (int q = 0; q < 4; ++q) {
                    bf16x8 a = *reinterpret_cast<const bf16x8*>(
                        wv + (size_t)(q * 128 + kk) * 1024);
                    C[q] = __builtin_amdgcn_mfma_f32_16x16x32_bf16(a, bx, C[q], 0, 0, 0);
                }
            }
        }
        if (t > 0) {
            const char* hb = (const char*)hbuf[(t - 1) & 1];
#pragma unroll
            for (int kk = 0; kk < 8; ++kk) {
                bf16x8 bh = *reinterpret_cast<const bf16x8*>(
                    hb + j * 512 + ((kk * 64 + quad * 16) ^ (j << 4)));
#pragma unroll
                for (int q = 0; q < 4; ++q) {
                    bf16x8 a = *reinterpret_cast<const bf16x8*>(
                        wv + (size_t)(512 + q * 128 + kk) * 1024);
                    C[q] = __builtin_amdgcn_mfma_f32_16x16x32_bf16(a, bh, C[q], 0, 0, 0);
                }
            }
        }

        // ---- 3. stage x(t+1) into the other x buffer (read last step, safe)
        if (have_x)
            *(unsigned long long*)((char*)xbuf[(t + 1) & 1]
                + grow * 512 + ((gseg * 8) ^ (grow << 4))) = pack4(xv);

        // ---- 4. LSTM cell (lane-local: 4 units x 1 batch row)
        float hval[4];
        unsigned long long hpack = 0;
#pragma unroll
        for (int r = 0; r < 4; ++r) {
            float ig = sigm(C[0][r]);
            float fg = sigm(C[1][r]);
            float gg = tanh_f(C[2][r]);
            float og = sigm(C[3][r]);
            float c = fg * cst[r] + ig * gg;
            cst[r] = c;
            float h = og * tanh_f(c);
            hval[r] = h;
            union { unsigned long long u; bf16_t b[4]; } pk;
            pk.u = hpack; pk.b[r] = (bf16_t)h; hpack = pk.u;
        }
        *(unsigned long long*)((char*)hbuf[t & 1]
            + j * 512 + ((ulane * 2) ^ (j << 4))) = hpack;

        // ---- 5. out = h + img (coalesced f32x4)
        {
            f32x4 o;
#pragma unroll
            for (int r = 0; r < 4; ++r) o[r] = hval[r] + imgv[r];
            *reinterpret_cast<f32x4*>(out + ((size_t)t * BATCH + brow) * HID + ulane) = o;
        }

        // ---- 6. one barrier/step: h(t)/x(t+1) writes visible; also orders
        // this step's tile reads before next step's overwrites (dbl-buffered)
        __syncthreads();
    }
}

// ---------------------------------------------------------------------------
extern "C" void kernel_launch(void* const* d_in, const int* in_sizes, int n_in,
                              void* d_out, int out_size, void* d_ws, size_t ws_size,
                              hipStream_t stream) {
    const float* img_feature = (const float*)d_in[0];   // [1024, 2048] fp32
    const int*   caption     = (const int*)d_in[1];     // [64, 1024] int32
    const float* W_img       = (const float*)d_in[2];   // [256, 2048] fp32
    const float* b_img       = (const float*)d_in[3];   // [256] fp32
    const float* emb         = (const float*)d_in[4];   // [32000, 256] fp32
    const float* W_ih        = (const float*)d_in[5];   // [1024, 256] fp32
    const float* W_hh        = (const float*)d_in[6];   // [1024, 256] fp32
    const float* b_ih        = (const float*)d_in[7];   // [1024] fp32
    const float* b_hh        = (const float*)d_in[8];   // [1024] fp32
    float* out = (float*)d_out;                         // [64,1024,256] fp32

    uint8_t* ws = (uint8_t*)d_ws;
    unsigned long long* Wsw = (unsigned long long*)ws;            // 1MB fragment-major bf16 W
    float* IMG = (float*)(ws + (1 << 20));                        // 1MB f32 img table

    // prep writes every byte lstm reads -> no memset needed; stream order
    // guarantees prep completes before lstm starts.
    prep_kernel<<<256, 256, 0, stream>>>(img_feature, W_img, b_img, W_ih, W_hh, Wsw, IMG);
    lstm_kernel<<<64, 1024, 0, stream>>>(caption, emb, b_ih, b_hh, Wsw, IMG, out);
}

// Round 8
// 428.791 us; speedup vs baseline: 4.0768x; 4.0768x over previous
//
#include <hip/hip_runtime.h>
#include <stdint.h>

// Problem constants
#define TS 64
#define BATCH 1024
#define HID 256
#define IMGD 2048

typedef __bf16 bf16_t;
typedef bf16_t bf16x8 __attribute__((ext_vector_type(8)));
typedef float f32x4 __attribute__((ext_vector_type(4)));

// load 8 consecutive fp32 (16B-aligned) and convert to a bf16x8 MFMA fragment
static __device__ __forceinline__ bf16x8 cvt8(const float* __restrict__ p) {
    const f32x4 a = *reinterpret_cast<const f32x4*>(p);
    const f32x4 b = *reinterpret_cast<const f32x4*>(p + 4);
    bf16x8 r;
    r[0] = (bf16_t)a[0]; r[1] = (bf16_t)a[1]; r[2] = (bf16_t)a[2]; r[3] = (bf16_t)a[3];
    r[4] = (bf16_t)b[0]; r[5] = (bf16_t)b[1]; r[6] = (bf16_t)b[2]; r[7] = (bf16_t)b[3];
    return r;
}
static __device__ __forceinline__ uint16_t f2bf(float f) {
    union { float f; uint32_t i; } c; c.f = f;
    uint32_t i = c.i;
    i += 0x7fffu + ((i >> 16) & 1u);   // RNE
    return (uint16_t)(i >> 16);
}
static __device__ __forceinline__ float sigm(float x) { return 1.f / (1.f + __expf(-x)); }
static __device__ __forceinline__ float tanh_f(float x) { return 1.f - 2.f / (1.f + __expf(2.f * x)); }

static __device__ __forceinline__ unsigned long long ldw(const unsigned long long* p) {
    return __hip_atomic_load(p, __ATOMIC_RELAXED, __HIP_MEMORY_SCOPE_AGENT);
}
static __device__ __forceinline__ void stw(unsigned long long* p, unsigned long long v) {
    __hip_atomic_store(p, v, __ATOMIC_RELAXED, __HIP_MEMORY_SCOPE_AGENT);
}

// ---------------------------------------------------------------------------
// ROUND-12: back to the measured-best family (r2: 4-block group, register
// weights, 363us dispatch) with ONE change: TAGGED SELF-VALIDATING EXCHANGE.
//
// r7 evidence: weight streaming dies on L2 thrash (FETCH 68MB -> 1.65GB) ->
// weights must live in registers -> 4-block group is structural. Its cost
// was the serial flag chain: h store -> vmcnt ack -> barrier -> flag store
// -> flag visibility -> poll -> co-load -> data (~4 MALL hops/step). r5/r7
// proved polls/overlap don't matter; sc0 L2-path rounds died on harness.
//
// This round: each lane publishes its 4 h bf16 as TWO u64 atomic words with
// an explicit 16-bit timestep tag INSIDE each word:
//   word0 = h0 | h1<<16 | h2<<32 | tag<<48
//   word1 = h3 | tag<<16
// Consumers poll the data words directly until tag==t: data usable the
// moment the store is visible -> ONE hop. No flags, no fences, no cross-
// address ordering assumptions (every word atomic + self-contained). Full
// bf16 precision kept. Blocks decouple from lockstep (steps pipeline).
//
// Safety argument (no hang possible):
//  - producers store unconditionally each step -> every poll terminates.
//  - double-buffer overwrite invariant: block P stores h(t) into buf[t&1]
//    only after observing peers' tag==t (their h(t-1)), which a peer
//    publishes only AFTER its step-(t-1) reads of buf[t&1]@t-2 completed
//    (loads drain before its MFMA/cell in program order). Induction holds.
//  - tags: expected values 1..64; buffer memset to 0 in-stream each launch
//    (also kills 0xAA poison and stale tags from previous launches).
//
// Everything else is the verified r2 kernel: img prologue, AGPR weight
// fragments (static indices!, round-4 lesson), XOR-swizzled LDS h tile,
// own chunk LDS-direct (never round-trips the MALL), 2 barriers/step.
// ---------------------------------------------------------------------------
#define WORDS_PER_BUF (64 * 4 * 16 * 16 * 2)   // groups*chunks*rows*slots*2

__global__ __launch_bounds__(256, 1) void lstm_kernel(
    const float* __restrict__ img_feature, const int* __restrict__ caption,
    const float* __restrict__ W_img, const float* __restrict__ b_img,
    const float* __restrict__ emb,
    const float* __restrict__ W_ih, const float* __restrict__ W_hh,
    const float* __restrict__ b_ih, const float* __restrict__ b_hh,
    unsigned long long* __restrict__ htag, float* __restrict__ out)
{
    const int g = blockIdx.x & 63, ch = blockIdx.x >> 6;
    const int b0 = g * 16, u0 = ch * 64;
    const int w = threadIdx.x >> 6, lane = threadIdx.x & 63;
    const int quad = lane >> 4, j = lane & 15;
    const int uw = u0 + w * 16;          // wave's first unit (16-unit tile)
    const int ulane = uw + quad * 4;     // this lane's first unit (owns 4)
    const int brow = b0 + j;             // this lane's batch row

    // double-buffered 16-row x 512B h tile, XOR-swizzled (r2/r4-verified):
    // phys(row r, byte b) = r*512 + (b ^ (r<<4))
    __shared__ unsigned long long hlds[2][1024];

    // ---- img prologue (before persistent regs go live)
    float imgv[4];
    {
        f32x4 D = {};
        const float* aw = W_img + (size_t)(uw + j) * IMGD + quad * 8;
        const float* bx = img_feature + (size_t)brow * IMGD + quad * 8;
        for (int kk = 0; kk < 64; ++kk) {
            bf16x8 a = cvt8(aw + kk * 32);
            bf16x8 b = cvt8(bx + kk * 32);
            D = __builtin_amdgcn_mfma_f32_16x16x32_bf16(a, b, D, 0, 0, 0);
        }
#pragma unroll
        for (int r = 0; r < 4; ++r) {
            float v = D[r] + b_img[ulane + r];
            imgv[r] = v > 0.f ? v : 0.f;
        }
    }

    // ---- persistent weight A-fragments (live in AGPRs; static indices!)
    bf16x8 Aih[4][8], Ahh[4][8];
#pragma unroll
    for (int q = 0; q < 4; ++q) {
        const int r = q * HID + uw + j;
        const float* pih = W_ih + (size_t)r * HID + quad * 8;
        const float* phh = W_hh + (size_t)r * HID + quad * 8;
#pragma unroll
        for (int kk = 0; kk < 8; ++kk) {
            Aih[q][kk] = cvt8(pih + kk * 32);
            Ahh[q][kk] = cvt8(phh + kk * 32);
        }
    }
    f32x4 biasv[4];
#pragma unroll
    for (int q = 0; q < 4; ++q)
#pragma unroll
        for (int r = 0; r < 4; ++r)
            biasv[q][r] = b_ih[q * HID + ulane + r] + b_hh[q * HID + ulane + r];

    float cst[4] = {0.f, 0.f, 0.f, 0.f};

    // ---- x B-fragments for t=0
    bf16x8 Bx[8], Bxn[8];
    {
        int cap = caption[brow];
        const float* px = emb + (size_t)cap * HID + quad * 8;
#pragma unroll
        for (int kk = 0; kk < 8; ++kk) Bx[kk] = cvt8(px + kk * 32);
    }

    // word indexing: htag[buf][g][chunk][row 16][slot 16][2]
    const int p0 = (ch + 1) & 3, p1 = (ch + 2) & 3, p2 = (ch + 3) & 3;
    const int cr = (int)threadIdx.x >> 4;   // consumer row 0..15
    const int ck = (int)threadIdx.x & 15;   // consumer slot 0..15
    const size_t gbase = (size_t)g * (4 * 16 * 16 * 2);
    const size_t i0 = gbase + (((size_t)p0 * 16 + cr) * 16 + ck) * 2;
    const size_t i1 = gbase + (((size_t)p1 * 16 + cr) * 16 + ck) * 2;
    const size_t i2 = gbase + (((size_t)p2 * 16 + cr) * 16 + ck) * 2;
    // producer: row j, slot = w*4+quad (unit (w*16+quad*4)/4 within chunk)
    const size_t ip = gbase + (((size_t)ch * 16 + j) * 16 + (w * 4 + quad)) * 2;

    for (int t = 0; t < TS; ++t) {
        f32x4 C[4];
#pragma unroll
        for (int q = 0; q < 4; ++q) C[q] = biasv[q];

        // ---- x_t MFMAs (independent of h; overlaps peers' store latency)
#pragma unroll
        for (int kk = 0; kk < 8; ++kk) {
#pragma unroll
            for (int q = 0; q < 4; ++q)
                C[q] = __builtin_amdgcn_mfma_f32_16x16x32_bf16(Aih[q][kk], Bx[kk], C[q], 0, 0, 0);
        }

        // ---- prefetch next step's embedding row (r2 style)
        {
            int tn = (t + 1 < TS) ? t + 1 : t;
            int cap = caption[tn * BATCH + brow];
            const float* px = emb + (size_t)cap * HID + quad * 8;
#pragma unroll
            for (int kk = 0; kk < 8; ++kk) Bxn[kk] = cvt8(px + kk * 32);
        }

        if (t > 0) {
            // ---- poll the 6 tagged peer words until all carry tag==t
            const unsigned long long* hb = htag + (size_t)((t - 1) & 1) * WORDS_PER_BUF;
            const unsigned long long tg = (unsigned long long)t;
            unsigned long long a0, a1, b0v, b1v, d0, d1;
            for (;;) {
                a0 = ldw(hb + i0); a1 = ldw(hb + i0 + 1);
                b0v = ldw(hb + i1); b1v = ldw(hb + i1 + 1);
                d0 = ldw(hb + i2); d1 = ldw(hb + i2 + 1);
                if ((a0 >> 48) == tg && ((a1 >> 16) & 0xFFFFu) == tg &&
                    (b0v >> 48) == tg && ((b1v >> 16) & 0xFFFFu) == tg &&
                    (d0 >> 48) == tg && ((d1 >> 16) & 0xFFFFu) == tg) break;
            }

            // ---- stage the 3 peer chunks into tile[(t-1)&1]
            char* tb = (char*)hlds[(t - 1) & 1];
            unsigned long long hp0 = (a0 & 0x0000FFFFFFFFFFFFull) | ((a1 & 0xFFFFull) << 48);
            unsigned long long hp1 = (b0v & 0x0000FFFFFFFFFFFFull) | ((b1v & 0xFFFFull) << 48);
            unsigned long long hp2 = (d0 & 0x0000FFFFFFFFFFFFull) | ((d1 & 0xFFFFull) << 48);
            *(unsigned long long*)(tb + cr * 512 + ((p0 * 128 + ck * 8) ^ (cr << 4))) = hp0;
            *(unsigned long long*)(tb + cr * 512 + ((p1 * 128 + ck * 8) ^ (cr << 4))) = hp1;
            *(unsigned long long*)(tb + cr * 512 + ((p2 * 128 + ck * 8) ^ (cr << 4))) = hp2;
            __syncthreads();   // stage complete (own chunk written last step)

            // ---- Hall ds_reads + hh-MFMA
            const char* rb = (const char*)hlds[(t - 1) & 1];
            bf16x8 Hall[8];
#pragma unroll
            for (int kk = 0; kk < 8; ++kk) {
                const int phys = j * 512 + ((kk * 64 + quad * 16) ^ (j << 4));
                Hall[kk] = *reinterpret_cast<const bf16x8*>(rb + phys);
            }
#pragma unroll
            for (int kk = 0; kk < 8; ++kk) {
#pragma unroll
                for (int q = 0; q < 4; ++q)
                    C[q] = __builtin_amdgcn_mfma_f32_16x16x32_bf16(Ahh[q][kk], Hall[kk], C[q], 0, 0, 0);
            }
        }

        // ---- LSTM cell (lane-local: 4 units x 1 batch row)
        float hval[4];
        unsigned long long hpack = 0;
#pragma unroll
        for (int r = 0; r < 4; ++r) {
            float ig = sigm(C[0][r]);
            float fg = sigm(C[1][r]);
            float gg = tanh_f(C[2][r]);
            float og = sigm(C[3][r]);
            float c = fg * cst[r] + ig * gg;
            cst[r] = c;
            float h = og * tanh_f(c);
            hval[r] = h;
            hpack |= ((unsigned long long)f2bf(h)) << (16 * r);
        }

        // ---- publish h(t): two tagged u64 atomic words (tag = t+1), plus
        //      own chunk LDS-direct for our own block's next step
        {
            const unsigned long long tag = (unsigned long long)(t + 1);
            unsigned long long w0v = (hpack & 0x0000FFFFFFFFFFFFull) | (tag << 48);
            unsigned long long w1v = (hpack >> 48) | (tag << 16);
            unsigned long long* hw = htag + (size_t)(t & 1) * WORDS_PER_BUF + ip;
            stw(hw, w0v);
            stw(hw + 1, w1v);
            char* tb = (char*)hlds[t & 1];
            *(unsigned long long*)(tb + j * 512 + ((ulane * 2) ^ (j << 4))) = hpack;
        }

        // ---- out store: coalesced f32x4
        {
            f32x4 o;
#pragma unroll
            for (int r = 0; r < 4; ++r) o[r] = hval[r] + imgv[r];
            *reinterpret_cast<f32x4*>(out + ((size_t)t * BATCH + brow) * HID + ulane) = o;
        }

        // end-of-step barrier: own-h LDS write visible block-wide; orders
        // LDS double-buffer reuse across steps
        __syncthreads();

#pragma unroll
        for (int kk = 0; kk < 8; ++kk) Bx[kk] = Bxn[kk];
    }
}

// ---------------------------------------------------------------------------
extern "C" void kernel_launch(void* const* d_in, const int* in_sizes, int n_in,
                              void* d_out, int out_size, void* d_ws, size_t ws_size,
                              hipStream_t stream) {
    const float* img_feature = (const float*)d_in[0];   // [1024, 2048] fp32
    const int*   caption     = (const int*)d_in[1];     // [64, 1024] int32
    const float* W_img       = (const float*)d_in[2];   // [256, 2048] fp32
    const float* b_img       = (const float*)d_in[3];   // [256] fp32
    const float* emb         = (const float*)d_in[4];   // [32000, 256] fp32
    const float* W_ih        = (const float*)d_in[5];   // [1024, 256] fp32
    const float* W_hh        = (const float*)d_in[6];   // [1024, 256] fp32
    const float* b_ih        = (const float*)d_in[7];   // [1024] fp32
    const float* b_hh        = (const float*)d_in[8];   // [1024] fp32
    float* out = (float*)d_out;                         // [64,1024,256] fp32

    // tagged h exchange buffer: 2 bufs x 1MB (64 groups x 4 chunks x 16 rows
    // x 16 slots x 2 u64). Zeroed in-stream each launch: tags become 0,
    // expected tags are 1..64 -> poison/stale-launch safe.
    unsigned long long* htag = (unsigned long long*)d_ws;
    hipMemsetAsync(htag, 0, (size_t)2 * WORDS_PER_BUF * 8, stream);

    lstm_kernel<<<256, 256, 0, stream>>>(img_feature, caption, W_img, b_img, emb,
                                         W_ih, W_hh, b_ih, b_hh, htag, out);
}

// Round 9
// 421.491 us; speedup vs baseline: 4.1474x; 1.0173x over previous
//
#include <hip/hip_runtime.h>
#include <stdint.h>

// Problem constants
#define TS 64
#define BATCH 1024
#define HID 256
#define IMGD 2048

typedef __bf16 bf16_t;
typedef bf16_t bf16x8 __attribute__((ext_vector_type(8)));
typedef float f32x4 __attribute__((ext_vector_type(4)));

// load 8 consecutive fp32 (16B-aligned) and convert to a bf16x8 MFMA fragment
static __device__ __forceinline__ bf16x8 cvt8(const float* __restrict__ p) {
    const f32x4 a = *reinterpret_cast<const f32x4*>(p);
    const f32x4 b = *reinterpret_cast<const f32x4*>(p + 4);
    bf16x8 r;
    r[0] = (bf16_t)a[0]; r[1] = (bf16_t)a[1]; r[2] = (bf16_t)a[2]; r[3] = (bf16_t)a[3];
    r[4] = (bf16_t)b[0]; r[5] = (bf16_t)b[1]; r[6] = (bf16_t)b[2]; r[7] = (bf16_t)b[3];
    return r;
}
// convert two raw f32x4 registers to a bf16x8 fragment (deferred-cvt path)
static __device__ __forceinline__ bf16x8 cvt8r(f32x4 a, f32x4 b) {
    bf16x8 r;
    r[0] = (bf16_t)a[0]; r[1] = (bf16_t)a[1]; r[2] = (bf16_t)a[2]; r[3] = (bf16_t)a[3];
    r[4] = (bf16_t)b[0]; r[5] = (bf16_t)b[1]; r[6] = (bf16_t)b[2]; r[7] = (bf16_t)b[3];
    return r;
}
static __device__ __forceinline__ uint16_t f2bf(float f) {
    union { float f; uint32_t i; } c; c.f = f;
    uint32_t i = c.i;
    i += 0x7fffu + ((i >> 16) & 1u);   // RNE
    return (uint16_t)(i >> 16);
}
static __device__ __forceinline__ float sigm(float x) { return 1.f / (1.f + __expf(-x)); }
static __device__ __forceinline__ float tanh_f(float x) { return 1.f - 2.f / (1.f + __expf(2.f * x)); }

static __device__ __forceinline__ unsigned long long ldw(const unsigned long long* p) {
    return __hip_atomic_load(p, __ATOMIC_RELAXED, __HIP_MEMORY_SCOPE_AGENT);
}
static __device__ __forceinline__ void stw(unsigned long long* p, unsigned long long v) {
    __hip_atomic_store(p, v, __ATOMIC_RELAXED, __HIP_MEMORY_SCOPE_AGENT);
}

// LDS-only barrier: waits lgkmcnt(0) (DS ops visible block-wide) but leaves
// vmem (global loads/stores) IN FLIGHT across the barrier. __syncthreads
// would emit s_waitcnt vmcnt(0) before s_barrier (compiler-conservative),
// serializing the emb gather + MALL store acks into the critical path every
// step. The tagged exchange needs no vmem ordering at barriers: exchanged
// words are self-validating, and our own next poll's vmcnt(0) drains our
// stores naturally. sched_barrier(0) on both sides pins LDS ops (rule #18).
static __device__ __forceinline__ void barrier_lds() {
    __builtin_amdgcn_sched_barrier(0);
    asm volatile("s_waitcnt lgkmcnt(0)" ::: "memory");
    __builtin_amdgcn_sched_barrier(0);
    __builtin_amdgcn_s_barrier();
    __builtin_amdgcn_sched_barrier(0);
}

// ---------------------------------------------------------------------------
// ROUND-13 = r8 (tagged self-validating exchange, verified 365us dispatch)
// + removal of the two per-step vmcnt(0) barrier drains.
//
// Evidence chain: r5 (poll pressure) neutral, r7 (issue overlap) neutral,
// r8 (4 hops -> 1 hop) NEUTRAL -- so the ~13.7k cy/step floor is none of
// those. What all variants shared: __syncthreads' implicit vmcnt(0) drain,
// paid twice per step: (1) stage barrier drains the 8 in-flight emb-gather
// loads (~900cy; also explains r4's deferred-cvt neutrality -- the barrier
// re-serialized the gather) + unacked htag stores; (2) end-of-step barrier
// drains the out HBM store + htag MALL acks (~1kcy). Neither drain is
// semantically needed (see barrier_lds comment). This round: lgkmcnt-only
// barriers + deferred gather cvt (raw f32x4 until after the stage barrier)
// -- the two only pay together.
//
// Tagged exchange (r8, verified): each lane publishes its 4 h bf16 as TWO
// u64 atomic words with a 16-bit step tag inside each:
//   word0 = h0|h1<<16|h2<<32|tag<<48 ; word1 = h3|tag<<16
// Consumers poll data words until tag==t. No flags, no cross-address
// ordering. Hang-impossible: producers store unconditionally; double-buffer
// overwrite invariant by induction (see r8 header). Tags 1..64; buffer
// memset 0 in-stream (poison-safe).
//
// CRITICAL: all register-array indices compile-time constant (round-4
// lesson: runtime indexing demotes to scratch -> 790MB HBM refetch).
// ---------------------------------------------------------------------------
#define WORDS_PER_BUF (64 * 4 * 16 * 16 * 2)   // groups*chunks*rows*slots*2

__global__ __launch_bounds__(256, 1) void lstm_kernel(
    const float* __restrict__ img_feature, const int* __restrict__ caption,
    const float* __restrict__ W_img, const float* __restrict__ b_img,
    const float* __restrict__ emb,
    const float* __restrict__ W_ih, const float* __restrict__ W_hh,
    const float* __restrict__ b_ih, const float* __restrict__ b_hh,
    unsigned long long* __restrict__ htag, float* __restrict__ out)
{
    const int g = blockIdx.x & 63, ch = blockIdx.x >> 6;
    const int b0 = g * 16, u0 = ch * 64;
    const int w = threadIdx.x >> 6, lane = threadIdx.x & 63;
    const int quad = lane >> 4, j = lane & 15;
    const int uw = u0 + w * 16;          // wave's first unit (16-unit tile)
    const int ulane = uw + quad * 4;     // this lane's first unit (owns 4)
    const int brow = b0 + j;             // this lane's batch row

    // double-buffered 16-row x 512B h tile, XOR-swizzled (r2/r4/r8-verified):
    // phys(row r, byte b) = r*512 + (b ^ (r<<4))
    __shared__ unsigned long long hlds[2][1024];

    // ---- img prologue (before persistent regs go live)
    float imgv[4];
    {
        f32x4 D = {};
        const float* aw = W_img + (size_t)(uw + j) * IMGD + quad * 8;
        const float* bx = img_feature + (size_t)brow * IMGD + quad * 8;
        for (int kk = 0; kk < 64; ++kk) {
            bf16x8 a = cvt8(aw + kk * 32);
            bf16x8 b = cvt8(bx + kk * 32);
            D = __builtin_amdgcn_mfma_f32_16x16x32_bf16(a, b, D, 0, 0, 0);
        }
#pragma unroll
        for (int r = 0; r < 4; ++r) {
            float v = D[r] + b_img[ulane + r];
            imgv[r] = v > 0.f ? v : 0.f;
        }
    }

    // ---- persistent weight A-fragments (live in AGPRs; static indices!)
    bf16x8 Aih[4][8], Ahh[4][8];
#pragma unroll
    for (int q = 0; q < 4; ++q) {
        const int r = q * HID + uw + j;
        const float* pih = W_ih + (size_t)r * HID + quad * 8;
        const float* phh = W_hh + (size_t)r * HID + quad * 8;
#pragma unroll
        for (int kk = 0; kk < 8; ++kk) {
            Aih[q][kk] = cvt8(pih + kk * 32);
            Ahh[q][kk] = cvt8(phh + kk * 32);
        }
    }
    f32x4 biasv[4];
#pragma unroll
    for (int q = 0; q < 4; ++q)
#pragma unroll
        for (int r = 0; r < 4; ++r)
            biasv[q][r] = b_ih[q * HID + ulane + r] + b_hh[q * HID + ulane + r];

    float cst[4] = {0.f, 0.f, 0.f, 0.f};

    // ---- x B-fragments for t=0
    bf16x8 Bx[8];
    {
        int cap = caption[brow];
        const float* px = emb + (size_t)cap * HID + quad * 8;
#pragma unroll
        for (int kk = 0; kk < 8; ++kk) Bx[kk] = cvt8(px + kk * 32);
    }

    // word indexing: htag[buf][g][chunk][row 16][slot 16][2]
    const int p0 = (ch + 1) & 3, p1 = (ch + 2) & 3, p2 = (ch + 3) & 3;
    const int cr = (int)threadIdx.x >> 4;   // consumer row 0..15
    const int ck = (int)threadIdx.x & 15;   // consumer slot 0..15
    const size_t gbase = (size_t)g * (4 * 16 * 16 * 2);
    const size_t i0 = gbase + (((size_t)p0 * 16 + cr) * 16 + ck) * 2;
    const size_t i1 = gbase + (((size_t)p1 * 16 + cr) * 16 + ck) * 2;
    const size_t i2 = gbase + (((size_t)p2 * 16 + cr) * 16 + ck) * 2;
    // producer: row j, slot = w*4+quad (unit (w*16+quad*4)/4 within chunk)
    const size_t ip = gbase + (((size_t)ch * 16 + j) * 16 + (w * 4 + quad)) * 2;

    for (int t = 0; t < TS; ++t) {
        // ---- 1. ISSUE raw f32 gather of x(t+1); cvt deferred so the loads
        //         stay in flight through the poll AND the stage barrier
        f32x4 xr[16];
        {
            int tn = (t + 1 < TS) ? t + 1 : t;
            int cap = caption[tn * BATCH + brow];
            const float* px = emb + (size_t)cap * HID + quad * 8;
#pragma unroll
            for (int kk = 0; kk < 8; ++kk) {
                xr[2 * kk]     = *reinterpret_cast<const f32x4*>(px + kk * 32);
                xr[2 * kk + 1] = *reinterpret_cast<const f32x4*>(px + kk * 32 + 4);
            }
        }

        // ---- 2. x_t MFMAs (independent of h)
        f32x4 C[4];
#pragma unroll
        for (int q = 0; q < 4; ++q) C[q] = biasv[q];
#pragma unroll
        for (int kk = 0; kk < 8; ++kk) {
#pragma unroll
            for (int q = 0; q < 4; ++q)
                C[q] = __builtin_amdgcn_mfma_f32_16x16x32_bf16(Aih[q][kk], Bx[kk], C[q], 0, 0, 0);
        }

        if (t > 0) {
            // ---- 3. poll the 6 tagged peer words until all carry tag==t
            const unsigned long long* hb = htag + (size_t)((t - 1) & 1) * WORDS_PER_BUF;
            const unsigned long long tg = (unsigned long long)t;
            unsigned long long a0, a1, b0v, b1v, d0, d1;
            for (;;) {
                a0 = ldw(hb + i0); a1 = ldw(hb + i0 + 1);
                b0v = ldw(hb + i1); b1v = ldw(hb + i1 + 1);
                d0 = ldw(hb + i2); d1 = ldw(hb + i2 + 1);
                if ((a0 >> 48) == tg && ((a1 >> 16) & 0xFFFFu) == tg &&
                    (b0v >> 48) == tg && ((b1v >> 16) & 0xFFFFu) == tg &&
                    (d0 >> 48) == tg && ((d1 >> 16) & 0xFFFFu) == tg) break;
            }

            // ---- 4. stage the 3 peer chunks into tile[(t-1)&1]
            char* tb = (char*)hlds[(t - 1) & 1];
            unsigned long long hp0 = (a0 & 0x0000FFFFFFFFFFFFull) | ((a1 & 0xFFFFull) << 48);
            unsigned long long hp1 = (b0v & 0x0000FFFFFFFFFFFFull) | ((b1v & 0xFFFFull) << 48);
            unsigned long long hp2 = (d0 & 0x0000FFFFFFFFFFFFull) | ((d1 & 0xFFFFull) << 48);
            *(unsigned long long*)(tb + cr * 512 + ((p0 * 128 + ck * 8) ^ (cr << 4))) = hp0;
            *(unsigned long long*)(tb + cr * 512 + ((p1 * 128 + ck * 8) ^ (cr << 4))) = hp1;
            *(unsigned long long*)(tb + cr * 512 + ((p2 * 128 + ck * 8) ^ (cr << 4))) = hp2;

            // LDS-only barrier: emb-gather loads stay IN FLIGHT across it
            barrier_lds();

            // ---- 5. Hall ds_reads; gather cvt scheduled under ds latency
            const char* rb = (const char*)hlds[(t - 1) & 1];
            bf16x8 Hall[8];
#pragma unroll
            for (int kk = 0; kk < 8; ++kk) {
                const int phys = j * 512 + ((kk * 64 + quad * 16) ^ (j << 4));
                Hall[kk] = *reinterpret_cast<const bf16x8*>(rb + phys);
            }
#pragma unroll
            for (int kk = 0; kk < 8; ++kk) Bx[kk] = cvt8r(xr[2 * kk], xr[2 * kk + 1]);

#pragma unroll
            for (int kk = 0; kk < 8; ++kk) {
#pragma unroll
                for (int q = 0; q < 4; ++q)
                    C[q] = __builtin_amdgcn_mfma_f32_16x16x32_bf16(Ahh[q][kk], Hall[kk], C[q], 0, 0, 0);
            }
        } else {
            // t==0: just convert the gathered x(1)
#pragma unroll
            for (int kk = 0; kk < 8; ++kk) Bx[kk] = cvt8r(xr[2 * kk], xr[2 * kk + 1]);
        }

        // ---- 6. LSTM cell (lane-local: 4 units x 1 batch row)
        float hval[4];
        unsigned long long hpack = 0;
#pragma unroll
        for (int r = 0; r < 4; ++r) {
            float ig = sigm(C[0][r]);
            float fg = sigm(C[1][r]);
            float gg = tanh_f(C[2][r]);
            float og = sigm(C[3][r]);
            float c = fg * cst[r] + ig * gg;
            cst[r] = c;
            float h = og * tanh_f(c);
            hval[r] = h;
            hpack |= ((unsigned long long)f2bf(h)) << (16 * r);
        }

        // ---- 7. publish h(t): two tagged u64 words (tag=t+1) to MALL +
        //         own chunk LDS-direct. Stores drain lazily (next poll's
        //         vmcnt(0) covers them) -- no barrier drain needed.
        {
            const unsigned long long tag = (unsigned long long)(t + 1);
            unsigned long long w0v = (hpack & 0x0000FFFFFFFFFFFFull) | (tag << 48);
            unsigned long long w1v = (hpack >> 48) | (tag << 16);
            unsigned long long* hw = htag + (size_t)(t & 1) * WORDS_PER_BUF + ip;
            stw(hw, w0v);
            stw(hw + 1, w1v);
            char* tb = (char*)hlds[t & 1];
            *(unsigned long long*)(tb + j * 512 + ((ulane * 2) ^ (j << 4))) = hpack;
        }

        // ---- 8. out store: coalesced f32x4 (stays in flight past barrier)
        {
            f32x4 o;
#pragma unroll
            for (int r = 0; r < 4; ++r) o[r] = hval[r] + imgv[r];
            *reinterpret_cast<f32x4*>(out + ((size_t)t * BATCH + brow) * HID + ulane) = o;
        }

        // ---- 9. LDS-only end-of-step barrier (orders hlds double-buffer)
        barrier_lds();
    }
}

// ---------------------------------------------------------------------------
extern "C" void kernel_launch(void* const* d_in, const int* in_sizes, int n_in,
                              void* d_out, int out_size, void* d_ws, size_t ws_size,
                              hipStream_t stream) {
    const float* img_feature = (const float*)d_in[0];   // [1024, 2048] fp32
    const int*   caption     = (const int*)d_in[1];     // [64, 1024] int32
    const float* W_img       = (const float*)d_in[2];   // [256, 2048] fp32
    const float* b_img       = (const float*)d_in[3];   // [256] fp32
    const float* emb         = (const float*)d_in[4];   // [32000, 256] fp32
    const float* W_ih        = (const float*)d_in[5];   // [1024, 256] fp32
    const float* W_hh        = (const float*)d_in[6];   // [1024, 256] fp32
    const float* b_ih        = (const float*)d_in[7];   // [1024] fp32
    const float* b_hh        = (const float*)d_in[8];   // [1024] fp32
    float* out = (float*)d_out;                         // [64,1024,256] fp32

    // tagged h exchange buffer: 2 bufs x 1MB (64 groups x 4 chunks x 16 rows
    // x 16 slots x 2 u64). Zeroed in-stream each launch: tags become 0,
    // expected tags are 1..64 -> poison/stale-launch safe.
    unsigned long long* htag = (unsigned long long*)d_ws;
    hipMemsetAsync(htag, 0, (size_t)2 * WORDS_PER_BUF * 8, stream);

    lstm_kernel<<<256, 256, 0, stream>>>(img_feature, caption, W_img, b_img, emb,
                                         W_ih, W_hh, b_ih, b_hh, htag, out);
}